// Round 6
// baseline (292.467 us; speedup 1.0000x reference)
//
#include <hip/hip_runtime.h>
#include <cstddef>
#include <cstdint>

#define S_LEN 2048
#define NHEAD 16
#define HDIM  64
#define EMB   1024
#define MROWS 4096

typedef short bf16x8 __attribute__((ext_vector_type(8)));
typedef float f32x4 __attribute__((ext_vector_type(4)));

// round-to-nearest fp32->bf16: 2 VALU ops
__device__ __forceinline__ unsigned short f2bf(float f) {
  union { float f; unsigned u; } v; v.f = f;
  return (unsigned short)((v.u + 0x8000u) >> 16);
}
__device__ __forceinline__ unsigned pack2bf(float a, float b) {
  union { float f; unsigned u; } x, y; x.f = a; y.f = b;
  return ((x.u + 0x8000u) >> 16) | ((y.u + 0x8000u) & 0xFFFF0000u);
}

__device__ __forceinline__ f32x4 fzero() {
  f32x4 z = {0.0f, 0.0f, 0.0f, 0.0f};
  return z;
}

// async global->LDS, 16B per lane. LDS dest = wave-uniform base + lane*16.
__device__ __forceinline__ void gl_lds16(const void* g, void* l) {
  __builtin_amdgcn_global_load_lds(
      (const __attribute__((address_space(1))) void*)g,
      (__attribute__((address_space(3))) void*)l, 16, 0, 0);
}

// Cast x (4M), Wq,Wk,Wv,Wfc (1M each) fp32 -> bf16, contiguous dst.
__global__ __launch_bounds__(256) void cast_kernel(
    const float* __restrict__ x, const float* __restrict__ Wq,
    const float* __restrict__ Wk, const float* __restrict__ Wv,
    const float* __restrict__ Wfc, unsigned short* __restrict__ dst)
{
  size_t idx8 = (size_t)(blockIdx.x * 256 + threadIdx.x) * 8;
  unsigned seg = (unsigned)(idx8 >> 20);
  const float* src;
  size_t off;
  if (seg < 4) { src = x; off = idx8; }
  else {
    const float* w4[4] = {Wq, Wk, Wv, Wfc};
    src = w4[seg - 4];
    off = idx8 & 0xFFFFFu;
  }
  float4 a = *(const float4*)&src[off];
  float4 b = *(const float4*)&src[off + 4];
  uint4 p;
  p.x = pack2bf(a.x, a.y);
  p.y = pack2bf(a.z, a.w);
  p.z = pack2bf(b.x, b.y);
  p.w = pack2bf(b.z, b.w);
  *(uint4*)&dst[idx8] = p;
}

// QKV fused, m97-style async staging. z selects weight/bias/output set.
// z=0: Qhd [bh][s][d]; z=1: Khd [bh][s][d] + KTd [bh][d][s]; z=2: VTd [bh][d][s].
__global__ __launch_bounds__(256) void gemm_qkv(
    const unsigned short* __restrict__ A, const unsigned short* __restrict__ Wall,
    const float* __restrict__ bq, const float* __restrict__ bk,
    const float* __restrict__ bv, unsigned short* __restrict__ Qhd,
    unsigned short* __restrict__ Khd, unsigned short* __restrict__ KTd,
    unsigned short* __restrict__ VTd)
{
  __shared__ short As[128][32];
  __shared__ short Bs[128][32];
  const int z = blockIdx.z;
  const unsigned short* B = Wall + (size_t)z * 1048576;
  const float* bias = (z == 0) ? bq : (z == 1) ? bk : bv;
  unsigned short* Yh = (z == 0) ? Qhd : (z == 1) ? Khd : nullptr;
  unsigned short* Yt = (z == 1) ? KTd : (z == 2) ? VTd : nullptr;
  const int K = EMB;
  const int t = threadIdx.x;
  const int lane = t & 63, w = t >> 6;
  const int quad = lane >> 4, l16 = lane & 15;
  const int wr = w >> 1, wc = w & 1;
  const int m0 = blockIdx.y * 128, n0 = blockIdx.x * 128;
  // staging: wave w covers rows 32w..32w+31 via 2 insts of 1KB each
  const int srow = 32 * w + (lane >> 2);
  const int scol = (lane & 3) * 8;
  short* ldsA = &As[0][0] + 1024 * w;   // wave-uniform bases
  short* ldsB = &Bs[0][0] + 1024 * w;

  f32x4 acc[4][4];
#pragma unroll
  for (int i = 0; i < 4; ++i)
#pragma unroll
    for (int j = 0; j < 4; ++j) acc[i][j] = fzero();

  for (int k0 = 0; k0 < K; k0 += 32) {
    __syncthreads();
    gl_lds16(&A[(size_t)(m0 + srow) * K + k0 + scol], ldsA);
    gl_lds16(&A[(size_t)(m0 + srow + 16) * K + k0 + scol], ldsA + 512);
    gl_lds16(&B[(size_t)(n0 + srow) * K + k0 + scol], ldsB);
    gl_lds16(&B[(size_t)(n0 + srow + 16) * K + k0 + scol], ldsB + 512);
    __syncthreads();
    bf16x8 af[4], bfr[4];
#pragma unroll
    for (int i = 0; i < 4; ++i)
      af[i] = *(const bf16x8*)&As[64 * wr + 16 * i + l16][quad * 8];
#pragma unroll
    for (int j = 0; j < 4; ++j)
      bfr[j] = *(const bf16x8*)&Bs[64 * wc + 16 * j + l16][quad * 8];
#pragma unroll
    for (int i = 0; i < 4; ++i)
#pragma unroll
      for (int j = 0; j < 4; ++j)
        acc[i][j] = __builtin_amdgcn_mfma_f32_16x16x32_bf16(af[i], bfr[j], acc[i][j], 0, 0, 0);
  }

#pragma unroll
  for (int i = 0; i < 4; ++i) {
    int mb = m0 + 64 * wr + 16 * i + quad * 4;
#pragma unroll
    for (int j = 0; j < 4; ++j) {
      int n = n0 + 64 * wc + 16 * j + l16;
      float bvv = bias[n];
      int h = n >> 6, d = n & 63;
      if (Yh) {
#pragma unroll
        for (int r = 0; r < 4; ++r) {
          int m = mb + r;
          int b = m >> 11, s = m & 2047;
          Yh[((size_t)(b * NHEAD + h)) * 131072 + (size_t)s * 64 + d] =
              f2bf(acc[i][j][r] + bvv);
        }
      }
      if (Yt) {
        int b = mb >> 11, s = mb & 2047;
        uint2 pk;
        pk.x = pack2bf(acc[i][j][0] + bvv, acc[i][j][1] + bvv);
        pk.y = pack2bf(acc[i][j][2] + bvv, acc[i][j][3] + bvv);
        *(uint2*)&Yt[((size_t)(b * NHEAD + h)) * 131072 + (size_t)d * S_LEN + s] = pk;
      }
    }
  }
}

// Final: out = AO @ Wfc^T + bfc, fp32 out [M][N]. Same async staging.
__global__ __launch_bounds__(256) void gemm_fc(
    const unsigned short* __restrict__ A, const unsigned short* __restrict__ B,
    const float* __restrict__ bias, float* __restrict__ Yf)
{
  __shared__ short As[128][32];
  __shared__ short Bs[128][32];
  const int K = EMB, N = EMB;
  const int t = threadIdx.x;
  const int lane = t & 63, w = t >> 6;
  const int quad = lane >> 4, l16 = lane & 15;
  const int wr = w >> 1, wc = w & 1;
  const int m0 = blockIdx.y * 128, n0 = blockIdx.x * 128;
  const int srow = 32 * w + (lane >> 2);
  const int scol = (lane & 3) * 8;
  short* ldsA = &As[0][0] + 1024 * w;
  short* ldsB = &Bs[0][0] + 1024 * w;

  f32x4 acc[4][4];
#pragma unroll
  for (int i = 0; i < 4; ++i)
#pragma unroll
    for (int j = 0; j < 4; ++j) acc[i][j] = fzero();

  for (int k0 = 0; k0 < K; k0 += 32) {
    __syncthreads();
    gl_lds16(&A[(size_t)(m0 + srow) * K + k0 + scol], ldsA);
    gl_lds16(&A[(size_t)(m0 + srow + 16) * K + k0 + scol], ldsA + 512);
    gl_lds16(&B[(size_t)(n0 + srow) * K + k0 + scol], ldsB);
    gl_lds16(&B[(size_t)(n0 + srow + 16) * K + k0 + scol], ldsB + 512);
    __syncthreads();
    bf16x8 af[4], bfr[4];
#pragma unroll
    for (int i = 0; i < 4; ++i)
      af[i] = *(const bf16x8*)&As[64 * wr + 16 * i + l16][quad * 8];
#pragma unroll
    for (int j = 0; j < 4; ++j)
      bfr[j] = *(const bf16x8*)&Bs[64 * wc + 16 * j + l16][quad * 8];
#pragma unroll
    for (int i = 0; i < 4; ++i)
#pragma unroll
      for (int j = 0; j < 4; ++j)
        acc[i][j] = __builtin_amdgcn_mfma_f32_16x16x32_bf16(af[i], bfr[j], acc[i][j], 0, 0, 0);
  }

#pragma unroll
  for (int i = 0; i < 4; ++i) {
    int mb = m0 + 64 * wr + 16 * i + quad * 4;
#pragma unroll
    for (int j = 0; j < 4; ++j) {
      int n = n0 + 64 * wc + 16 * j + l16;
      float bvv = bias[n];
#pragma unroll
      for (int r = 0; r < 4; ++r)
        Yf[(size_t)(mb + r) * N + n] = acc[i][j][r] + bvv;
    }
  }
}

// Partial gram from KTd [bh][d][s]: block bx -> bh = bx>>2, part = bx&3.
__global__ __launch_bounds__(256) void gram_mfma(
    const unsigned short* __restrict__ KTh, float* __restrict__ gram_p)
{
  __shared__ short KTs[64][136];
  const int t = threadIdx.x;
  const int lane = t & 63, w = t >> 6;
  const int quad = lane >> 4, l16 = lane & 15;
  const int bh = blockIdx.x >> 2, part = blockIdx.x & 3;
  const unsigned short* Kb = KTh + (size_t)bh * 131072 + part * 512;

  f32x4 gacc[4];
#pragma unroll
  for (int j = 0; j < 4; ++j) gacc[j] = fzero();

  const int rv = t >> 4, cv = (t & 15) * 8;
  for (int st = 0; st < 4; ++st) {
    float4 vv[4];
#pragma unroll
    for (int r = 0; r < 4; ++r)
      vv[r] = *(const float4*)&Kb[(size_t)(rv + 16 * r) * S_LEN + st * 128 + cv];
    __syncthreads();
#pragma unroll
    for (int r = 0; r < 4; ++r)
      *(float4*)&KTs[rv + 16 * r][cv] = vv[r];
    __syncthreads();
#pragma unroll
    for (int c = 0; c < 4; ++c) {
      bf16x8 ai = *(const bf16x8*)&KTs[16 * w + l16][32 * c + quad * 8];
#pragma unroll
      for (int jb = 0; jb < 4; ++jb) {
        bf16x8 bj = *(const bf16x8*)&KTs[16 * jb + l16][32 * c + quad * 8];
        gacc[jb] = __builtin_amdgcn_mfma_f32_16x16x32_bf16(ai, bj, gacc[jb], 0, 0, 0);
      }
    }
  }
#pragma unroll
  for (int jb = 0; jb < 4; ++jb)
#pragma unroll
    for (int r = 0; r < 4; ++r)
      gram_p[(size_t)blockIdx.x * 4096 +
             (size_t)(16 * w + quad * 4 + r) * 64 + 16 * jb + l16] = gacc[jb][r];
}

// In-place Gauss-Jordan inverse, 64x64 SPD (diag-dominant, no pivoting).
__global__ __launch_bounds__(256) void inv_kernel(
    const float* __restrict__ gram_p, unsigned short* __restrict__ ginv)
{
  __shared__ float As[64][68];
  __shared__ float prow[2][64];
  __shared__ float fcol[2][64];
  const int bh = blockIdx.x;
  const int t = threadIdx.x;
  const int r = t >> 2;
  const int c0 = (t & 3) * 16;
  const float* G = gram_p + (size_t)bh * 4 * 4096;

  float4 g[4];
#pragma unroll
  for (int jj = 0; jj < 4; ++jj) {
    int off = r * 64 + c0 + 4 * jj;
    float4 s0 = *(const float4*)&G[off];
    float4 s1 = *(const float4*)&G[4096 + off];
    float4 s2 = *(const float4*)&G[8192 + off];
    float4 s3 = *(const float4*)&G[12288 + off];
    g[jj].x = (s0.x + s1.x) + (s2.x + s3.x);
    g[jj].y = (s0.y + s1.y) + (s2.y + s3.y);
    g[jj].z = (s0.z + s1.z) + (s2.z + s3.z);
    g[jj].w = (s0.w + s1.w) + (s2.w + s3.w);
    *(float4*)&As[r][c0 + 4 * jj] = g[jj];
  }
  if (c0 == 0) fcol[0][r] = g[0].x;
  if (r == 0) {
#pragma unroll
    for (int jj = 0; jj < 4; ++jj) *(float4*)&prow[0][c0 + 4 * jj] = g[jj];
  }
  __syncthreads();

  for (int k = 0; k < 64; ++k) {
    const int kb = k & 1;
    const float f = fcol[kb][r];
    const float ip = 1.0f / fcol[kb][k];
    const float fi = f * ip;
    const bool pr = (r == k);
    float4 nv[4];
#pragma unroll
    for (int jj = 0; jj < 4; ++jj) {
      float4 a = *(const float4*)&As[r][c0 + 4 * jj];
      float4 p = *(const float4*)&prow[kb][c0 + 4 * jj];
      float4 o;
      if (pr) {
        o.x = p.x * ip; o.y = p.y * ip; o.z = p.z * ip; o.w = p.w * ip;
      } else {
        o.x = fmaf(-fi, p.x, a.x); o.y = fmaf(-fi, p.y, a.y);
        o.z = fmaf(-fi, p.z, a.z); o.w = fmaf(-fi, p.w, a.w);
      }
      const int cb = c0 + 4 * jj;
      const float kv = pr ? ip : -fi;
      if (cb == k) o.x = kv;
      if (cb + 1 == k) o.y = kv;
      if (cb + 2 == k) o.z = kv;
      if (cb + 3 == k) o.w = kv;
      *(float4*)&As[r][c0 + 4 * jj] = o;
      nv[jj] = o;
    }
    if (k < 63) {
      const int nk = k + 1, nb = nk & 1;
      if (nk >= c0 && nk < c0 + 16) fcol[nb][r] = As[r][nk];
      if (r == nk) {
#pragma unroll
        for (int jj = 0; jj < 4; ++jj) *(float4*)&prow[nb][c0 + 4 * jj] = nv[jj];
      }
    }
    __syncthreads();
  }

  unsigned short* O = ginv + (size_t)bh * 4096;
#pragma unroll
  for (int jj = 0; jj < 4; ++jj) {
    float4 v = *(const float4*)&As[r][c0 + 4 * jj];
    uint2 pk;
    pk.x = pack2bf(v.x, v.y);
    pk.y = pack2bf(v.z, v.w);
    *(uint2*)&O[r * 64 + c0 + 4 * jj] = pk;
  }
}

// Fused flash, software-pipelined:
//  - Qp B-frags register-resident for the whole K-loop (invariant)
//  - V(kt) issued at iter top, consumed after S-MFMA+exp (~400 cyc hidden)
//  - K(kt+1) issued mid-iter, unconditional wrapped index (no scratch demotion)
//  - exp2f with log2(e)/32 folded into Qp
//  - 1D grid with XCD swizzle: all 32 qt-blocks of a bh share id%8 -> same XCD L2
__global__ __launch_bounds__(256, 4) void flash_mfma(
    const unsigned short* __restrict__ Qh, const unsigned short* __restrict__ Kh,
    const unsigned short* __restrict__ VTh, const unsigned short* __restrict__ Ginv,
    unsigned short* __restrict__ AO)
{
  __shared__ short Qps[64 * 72];      // [q][d], stride 72
  __shared__ short Ps[2][64 * 72];    // [q][key], stride 72, double-buffered
  __shared__ float Lred[4][64];
  const int t = threadIdx.x;
  const int lane = t & 63, w = t >> 6;
  const int quad = lane >> 4, l16 = lane & 15;
  const int id = blockIdx.x;
  const int qt = (id >> 3) & 31;
  const int bh = ((id >> 8) << 3) | (id & 7);
  const unsigned short* Qb = Qh + (size_t)bh * 131072;
  const unsigned short* Kb = Kh + (size_t)bh * 131072;
  const unsigned short* Vb = VTh + (size_t)bh * 131072;
  const unsigned short* Gb = Ginv + (size_t)bh * 4096;

  // ---- phase 0: Qp = (Q @ Ginv) * log2(e)/32 -> Qps; prefetch K(0) ----
  bf16x8 ak[2];
#pragma unroll
  for (int c = 0; c < 2; ++c)
    ak[c] = *(const bf16x8*)&Kb[(size_t)(16 * w + l16) * 64 + 32 * c + 8 * quad];
  {
    bf16x8 aq[2];
#pragma unroll
    for (int c = 0; c < 2; ++c)
      aq[c] = *(const bf16x8*)&Qb[(size_t)(qt * 64 + 16 * w + l16) * 64 + 32 * c + 8 * quad];
    f32x4 qacc[4];
#pragma unroll
    for (int nb = 0; nb < 4; ++nb) qacc[nb] = fzero();
#pragma unroll
    for (int c = 0; c < 2; ++c) {
#pragma unroll
      for (int nb = 0; nb < 4; ++nb) {
        // B[k=d][n=d'] = Ginv[d][d'] = Ginv[d'][d] (symmetric) -> row load
        bf16x8 bg = *(const bf16x8*)&Gb[(size_t)(16 * nb + l16) * 64 + 32 * c + 8 * quad];
        qacc[nb] = __builtin_amdgcn_mfma_f32_16x16x32_bf16(aq[c], bg, qacc[nb], 0, 0, 0);
      }
    }
    const float cs = 0.04508422e0f;  // log2(e)/32
#pragma unroll
    for (int nb = 0; nb < 4; ++nb)
#pragma unroll
      for (int r = 0; r < 4; ++r)
        Qps[(16 * w + 4 * quad + r) * 72 + 16 * nb + l16] =
            (short)f2bf(qacc[nb][r] * cs);
  }
  __syncthreads();

  // Qp^T B-frags: register-resident, loop-invariant
  bf16x8 bqf[2][4];
#pragma unroll
  for (int c = 0; c < 2; ++c)
#pragma unroll
    for (int qb = 0; qb < 4; ++qb)
      bqf[c][qb] = *(const bf16x8*)&Qps[(16 * qb + l16) * 72 + 32 * c + 8 * quad];

  f32x4 oacc[4];
#pragma unroll
  for (int qb = 0; qb < 4; ++qb) oacc[qb] = fzero();
  float lsum[4] = {0.0f, 0.0f, 0.0f, 0.0f};

  for (int kt = 0; kt < 32; ++kt) {
    // issue V(kt) now; consumed after barrier (S-MFMA + exp hide the latency)
    bf16x8 av[2];
#pragma unroll
    for (int c = 0; c < 2; ++c)
      av[c] = *(const bf16x8*)&Vb[(size_t)(16 * w + l16) * S_LEN + kt * 64 + 32 * c + 8 * quad];

    // S^T = K @ Qp^T : wave w owns keys [16w,16w+16) of this 64-key tile
    f32x4 sacc[4];
#pragma unroll
    for (int qb = 0; qb < 4; ++qb) sacc[qb] = fzero();
#pragma unroll
    for (int c = 0; c < 2; ++c)
#pragma unroll
      for (int qb = 0; qb < 4; ++qb)
        sacc[qb] = __builtin_amdgcn_mfma_f32_16x16x32_bf16(ak[c], bqf[c][qb], sacc[qb], 0, 0, 0);

    // prefetch K(kt+1), wrapped (unconditional -> stays in VGPRs)
    const int nk = (kt + 1) & 31;
#pragma unroll
    for (int c = 0; c < 2; ++c)
      ak[c] = *(const bf16x8*)&Kb[(size_t)(nk * 64 + 16 * w + l16) * 64 + 32 * c + 8 * quad];

    // P = 2^S -> Ps[buf]
    short* Pbuf = &Ps[kt & 1][0];
#pragma unroll
    for (int qb = 0; qb < 4; ++qb) {
      float e0 = exp2f(sacc[qb][0]);
      float e1 = exp2f(sacc[qb][1]);
      float e2 = exp2f(sacc[qb][2]);
      float e3 = exp2f(sacc[qb][3]);
      lsum[qb] += (e0 + e1) + (e2 + e3);
      uint2 pk;
      pk.x = pack2bf(e0, e1);
      pk.y = pack2bf(e2, e3);
      *(uint2*)&Pbuf[(16 * qb + l16) * 72 + 16 * w + 4 * quad] = pk;
    }
    __syncthreads();  // drains vmcnt: av, ak(kt+1) in regs; Ps visible

    // O^T += VT @ P^T : wave w owns d-rows [16w,16w+16)
#pragma unroll
    for (int c = 0; c < 2; ++c)
#pragma unroll
      for (int qb = 0; qb < 4; ++qb) {
        bf16x8 bp = *(const bf16x8*)&Pbuf[(16 * qb + l16) * 72 + 32 * c + 8 * quad];
        oacc[qb] = __builtin_amdgcn_mfma_f32_16x16x32_bf16(av[c], bp, oacc[qb], 0, 0, 0);
      }
    // no trailing barrier: next write targets the other Ps buffer
  }

  // ---- softmax denominator: reduce over quad (keys) then waves ----
#pragma unroll
  for (int qb = 0; qb < 4; ++qb) {
    lsum[qb] += __shfl_xor(lsum[qb], 16, 64);
    lsum[qb] += __shfl_xor(lsum[qb], 32, 64);
  }
  if (lane < 16)
#pragma unroll
    for (int qb = 0; qb < 4; ++qb) Lred[w][qb * 16 + l16] = lsum[qb];
  __syncthreads();
  if (t < 64)
    Lred[0][t] = 1.0f / (Lred[0][t] + Lred[1][t] + Lred[2][t] + Lred[3][t]);
  __syncthreads();

  // ---- epilogue: oacc[qb][r] = O^T[d=16w+4quad+r][q=16qb+l16], packed store ----
  const int b = bh >> 4, h = bh & 15;
#pragma unroll
  for (int qb = 0; qb < 4; ++qb) {
    float li = Lred[0][16 * qb + l16];
    int s = qt * 64 + 16 * qb + l16;
    size_t base = (size_t)b * S_LEN * EMB + (size_t)s * EMB + h * 64 + 16 * w + 4 * quad;
    uint2 pk;
    pk.x = pack2bf(oacc[qb][0] * li, oacc[qb][1] * li);
    pk.y = pack2bf(oacc[qb][2] * li, oacc[qb][3] * li);
    *(uint2*)&AO[base] = pk;
  }
}

extern "C" void kernel_launch(void* const* d_in, const int* in_sizes, int n_in,
                              void* d_out, int out_size, void* d_ws, size_t ws_size,
                              hipStream_t stream) {
  (void)in_sizes; (void)n_in; (void)out_size; (void)ws_size;
  const float* x   = (const float*)d_in[0];
  const float* Wq  = (const float*)d_in[1];
  const float* bq  = (const float*)d_in[2];
  const float* Wk  = (const float*)d_in[3];
  const float* bk  = (const float*)d_in[4];
  const float* Wv  = (const float*)d_in[5];
  const float* bv  = (const float*)d_in[6];
  const float* Wfc = (const float*)d_in[7];
  const float* bfc = (const float*)d_in[8];
  float* out = (float*)d_out;

  unsigned short* xb   = (unsigned short*)d_ws;            // [4096][1024]
  unsigned short* Wqb  = xb + (size_t)4194304;             // Wq,Wk,Wv,Wfc contiguous
  unsigned short* Wfcb = Wqb + 3 * 1048576;
  unsigned short* Qhd  = Wfcb + 1048576;                   // [32][2048][64]
  unsigned short* Khd  = Qhd + 4194304;
  unsigned short* KTd  = Khd + 4194304;                    // [32][64][2048]
  unsigned short* VTd  = KTd + 4194304;                    // [32][64][2048]
  unsigned short* AOd  = VTd + 4194304;                    // [2][2048][1024]
  float* gram_p        = (float*)(AOd + 4194304);          // [128][64][64] f32
  unsigned short* ginv = (unsigned short*)(gram_p + 524288); // [32][64][64] bf16

  cast_kernel<<<4096, 256, 0, stream>>>(x, Wq, Wk, Wv, Wfc, xb);
  gemm_qkv<<<dim3(8, 32, 3), 256, 0, stream>>>(xb, Wqb, bq, bk, bv,
                                               Qhd, Khd, KTd, VTd);
  gram_mfma<<<128, 256, 0, stream>>>(KTd, gram_p);
  inv_kernel<<<32, 256, 0, stream>>>(gram_p, ginv);
  flash_mfma<<<1024, 256, 0, stream>>>(Qhd, Khd, VTd, ginv, AOd);
  gemm_fc<<<dim3(8, 32), 256, 0, stream>>>(AOd, Wfcb, bfc, out);
}